// Round 1
// baseline (738.120 us; speedup 1.0000x reference)
//
#include <hip/hip_runtime.h>
#include <cstdint>
#include <cstddef>

typedef __attribute__((ext_vector_type(8))) short bf16x8;
typedef __attribute__((ext_vector_type(4))) float f32x4;

#define B_DIM 1024
#define L_SEQ 50
#define H_DIM 512
#define NITEM 50000

// fp32 -> bf16 round-to-nearest-even (finite inputs)
__device__ __forceinline__ unsigned short f2bf(float x) {
  unsigned u = __float_as_uint(x);
  return (unsigned short)((u + 0x7fffu + ((u >> 16) & 1u)) >> 16);
}
__device__ __forceinline__ unsigned pack2(float lo, float hi) {
  return (unsigned)f2bf(lo) | ((unsigned)f2bf(hi) << 16);
}

// ---------------- fused 3-table masked mean -> u (bf16 [B][H]) ----------------
__global__ void mean_kernel(const int* __restrict__ item_ids, const int* __restrict__ item_len,
                            const int* __restrict__ ent_ids, const int* __restrict__ ent_len,
                            const int* __restrict__ word_ids, const int* __restrict__ word_len,
                            const float* __restrict__ item_emb, const float* __restrict__ ent_emb,
                            const float* __restrict__ word_emb, unsigned short* __restrict__ u_bf) {
  const int b = blockIdx.x >> 1;
  const int col = ((blockIdx.x & 1) << 8) + threadIdx.x;  // 2 blocks cover H=512
  float out = 0.f;
  {
    const int len = item_len[b]; float a = 0.f;
#pragma unroll 4
    for (int l = 0; l < len; ++l) a += item_emb[(size_t)item_ids[b * L_SEQ + l] * H_DIM + col];
    out += a / (float)(len > 0 ? len : 1);
  }
  {
    const int len = ent_len[b]; float a = 0.f;
#pragma unroll 4
    for (int l = 0; l < len; ++l) a += ent_emb[(size_t)ent_ids[b * L_SEQ + l] * H_DIM + col];
    out += a / (float)(len > 0 ? len : 1);
  }
  {
    const int len = word_len[b]; float a = 0.f;
#pragma unroll 4
    for (int l = 0; l < len; ++l) a += word_emb[(size_t)word_ids[b * L_SEQ + l] * H_DIM + col];
    out += a / (float)(len > 0 ? len : 1);
  }
  u_bf[b * H_DIM + col] = f2bf(out / 3.f);
}

// ---------------- bf16 MFMA GEMM: C[M][N] = A[M][K](bf16) * B[K][N](f32->bf16) + bias ----------------
// 128x128 tile, BK=64, 4 waves (each 64x64), double-buffered LDS, 2-phase.
// EPI==0: relu + bf16 store (GEMM1).  EPI==1: f32 store (GEMM2 logits).
template <int K, int N, int EPI>
__global__ __launch_bounds__(256, 2) void gemm_bias(const unsigned short* __restrict__ Ag,
                                                    const float* __restrict__ Bg,
                                                    const float* __restrict__ bias,
                                                    unsigned short* __restrict__ Cbf,
                                                    float* __restrict__ Cf) {
  // A tile: [row m][64 k] bf16, XOR-swizzled 16B chunks (chunk ^= m&7) -> conflict-free b128 frag reads
  __shared__ unsigned short As[2][128 * 64];
  // B tile: pair-packed [kp=k/2][128 n] uint, column-XOR by ((kp>>2)&3)<<4 -> 2-way (free) b32 frag reads
  __shared__ unsigned Bp[2][32 * 128];

  const int tid = threadIdx.x;
  const int lane = tid & 63;
  const int wid = tid >> 6;
  const int m0 = blockIdx.x * 128;
  const int n0 = blockIdx.y * 128;

  uint4 areg[4];
  float4 breg[4][2];
  f32x4 acc[4][4] = {};

  const int arow = 32 * wid + (lane >> 3);  // + 8q
  const int acol = 8 * (lane & 7);          // element offset within 64-k row
  const int brow = 16 * wid + 2 * (lane >> 5);  // + 4i, then rows {+0,+1}
  const int bcol4 = 4 * (lane & 31);
  const int bcolg = (n0 + bcol4 < N - 4) ? (n0 + bcol4) : (N - 4);  // clamp ragged edge (valid, masked at store)

  auto stage_global = [&](int kt) {
    const int k0 = kt * 64;
#pragma unroll
    for (int q = 0; q < 4; ++q)
      areg[q] = *(const uint4*)&Ag[(size_t)(m0 + arow + 8 * q) * K + k0 + acol];
#pragma unroll
    for (int i = 0; i < 4; ++i) {
      const size_t ro = (size_t)(k0 + brow + 4 * i) * N + bcolg;
      breg[i][0] = *(const float4*)&Bg[ro];      // k even
      breg[i][1] = *(const float4*)&Bg[ro + N];  // k odd
    }
  };

  auto stage_lds = [&](int buf) {
#pragma unroll
    for (int q = 0; q < 4; ++q) {
      const int row = arow + 8 * q;
      *(uint4*)&As[buf][row * 64 + (acol ^ ((row & 7) * 8))] = areg[q];
    }
#pragma unroll
    for (int i = 0; i < 4; ++i) {
      const int kp = (brow >> 1) + 2 * i;  // 8w + 2i + h
      const int xr = ((kp >> 2) & 3) << 4;
      uint4 w;
      w.x = pack2(breg[i][0].x, breg[i][1].x);
      w.y = pack2(breg[i][0].y, breg[i][1].y);
      w.z = pack2(breg[i][0].z, breg[i][1].z);
      w.w = pack2(breg[i][0].w, breg[i][1].w);
      *(uint4*)&Bp[buf][kp * 128 + (bcol4 ^ xr)] = w;
    }
  };

  const int wr = wid >> 1, wc = wid & 1;
  const int mw = wr * 64, nw = wc * 64;
  const int l15 = lane & 15, kb = lane >> 4;

  auto compute = [&](int buf) {
#pragma unroll
    for (int koi = 0; koi < 2; ++koi) {  // two k-halves of 32
      const int ko = koi * 32;
      bf16x8 af[4], bf[4];
#pragma unroll
      for (int i = 0; i < 4; ++i) {
        const int row = mw + 16 * i + l15;
        af[i] = *(const bf16x8*)&As[buf][row * 64 + ((ko + 8 * kb) ^ ((row & 7) * 8))];
      }
#pragma unroll
      for (int j = 0; j < 4; ++j) {
        const int cc = (nw + 16 * j + l15) ^ (kb << 4);
        const int rb = (16 * koi + 4 * kb) * 128;
        uint4 uu;
        uu.x = Bp[buf][rb + cc];
        uu.y = Bp[buf][rb + 128 + cc];
        uu.z = Bp[buf][rb + 256 + cc];
        uu.w = Bp[buf][rb + 384 + cc];
        bf[j] = *(bf16x8*)&uu;
      }
#pragma unroll
      for (int i = 0; i < 4; ++i)
#pragma unroll
        for (int j = 0; j < 4; ++j)
          acc[i][j] = __builtin_amdgcn_mfma_f32_16x16x32_bf16(af[i], bf[j], acc[i][j], 0, 0, 0);
    }
  };

  const int NT = K / 64;
  stage_global(0);
  stage_lds(0);
  __syncthreads();
  for (int t = 0; t < NT; ++t) {
    const int cur = t & 1;
    if (t + 1 < NT) stage_global(t + 1);  // issue next-tile loads early (latency hides under MFMA)
    compute(cur);
    if (t + 1 < NT) stage_lds(cur ^ 1);   // vmcnt wait lands here, after compute
    __syncthreads();
  }

  // epilogue: C/D layout col=lane&15, row=(lane>>4)*4+reg  [verified m89/m91]
#pragma unroll
  for (int i = 0; i < 4; ++i) {
    const int rbase = m0 + mw + 16 * i + 4 * kb;
#pragma unroll
    for (int j = 0; j < 4; ++j) {
      const int cg = n0 + nw + 16 * j + l15;
      if (cg < N) {
        const float bv = bias[cg];
#pragma unroll
        for (int r = 0; r < 4; ++r) {
          const float v = acc[i][j][r] + bv;
          if (EPI == 0)
            Cbf[(size_t)(rbase + r) * N + cg] = f2bf(v > 0.f ? v : 0.f);
          else
            Cf[(size_t)(rbase + r) * N + cg] = v;
        }
      }
    }
  }
}

// ---------------- softmax pass 1: per-row online max & sumexp of logits ----------------
__global__ void smax1(const float* __restrict__ logits, float* __restrict__ rms) {
  const int b = blockIdx.x;
  const float4* p = (const float4*)(logits + (size_t)b * NITEM);
  float m = -3.4e38f, s = 0.f;
  for (int i = threadIdx.x; i < NITEM / 4; i += 256) {
    const float4 v = p[i];
    const float x[4] = {v.x, v.y, v.z, v.w};
#pragma unroll
    for (int j = 0; j < 4; ++j) {
      const float nm = fmaxf(m, x[j]);
      s = s * expf(m - nm) + expf(x[j] - nm);
      m = nm;
    }
  }
  __shared__ float sm[256], ss[256];
  sm[threadIdx.x] = m;
  ss[threadIdx.x] = s;
  __syncthreads();
  for (int off = 128; off > 0; off >>= 1) {
    if (threadIdx.x < off) {
      const float ma = sm[threadIdx.x], mb = sm[threadIdx.x + off];
      const float sa = ss[threadIdx.x], sb = ss[threadIdx.x + off];
      const float nm = fmaxf(ma, mb);
      sm[threadIdx.x] = nm;
      ss[threadIdx.x] = sa * expf(ma - nm) + sb * expf(mb - nm);
    }
    __syncthreads();
  }
  if (threadIdx.x == 0) {
    rms[b] = sm[0];
    rms[B_DIM + b] = ss[0];
  }
}

// ---------------- softmax pass 2: probs in-place + log_softmax(probs) at label ----------------
__global__ void smax2(float* __restrict__ buf, const float* __restrict__ rms,
                      const int* __restrict__ labels, float* __restrict__ row_lp) {
  const int b = blockIdx.x;
  float4* p = (float4*)(buf + (size_t)b * NITEM);
  const float m = rms[b];
  const float inv = 1.f / rms[B_DIM + b];
  const int lab = labels[b];
  __shared__ float s_pl;
  __shared__ float sm[256], ss[256];
  float m2 = -3.4e38f, s2 = 0.f;
  for (int i = threadIdx.x; i < NITEM / 4; i += 256) {
    const float4 v = p[i];
    float pr[4];
#pragma unroll
    for (int j = 0; j < 4; ++j) {
      pr[j] = expf((&v.x)[j] - m) * inv;
      const float nm = fmaxf(m2, pr[j]);
      s2 = s2 * expf(m2 - nm) + expf(pr[j] - nm);
      m2 = nm;
    }
    float4 w;
    w.x = pr[0]; w.y = pr[1]; w.z = pr[2]; w.w = pr[3];
    p[i] = w;
    const int base = 4 * i;
    if (lab >= base && lab < base + 4) s_pl = pr[lab - base];
  }
  sm[threadIdx.x] = m2;
  ss[threadIdx.x] = s2;
  __syncthreads();
  for (int off = 128; off > 0; off >>= 1) {
    if (threadIdx.x < off) {
      const float ma = sm[threadIdx.x], mb = sm[threadIdx.x + off];
      const float sa = ss[threadIdx.x], sb = ss[threadIdx.x + off];
      const float nm = fmaxf(ma, mb);
      sm[threadIdx.x] = nm;
      ss[threadIdx.x] = sa * expf(ma - nm) + sb * expf(mb - nm);
    }
    __syncthreads();
  }
  if (threadIdx.x == 0) row_lp[b] = s_pl - (sm[0] + logf(ss[0]));
}

// ---------------- finalize: labels (as float) + loss ----------------
__global__ void fin(const float* __restrict__ row_lp, const int* __restrict__ labels,
                    float* __restrict__ out) {
  __shared__ float sb[256];
  float a = 0.f;
  for (int i = threadIdx.x; i < B_DIM; i += 256) {
    a += row_lp[i];
    out[(size_t)B_DIM * NITEM + i] = (float)labels[i];
  }
  sb[threadIdx.x] = a;
  __syncthreads();
  for (int off = 128; off > 0; off >>= 1) {
    if (threadIdx.x < off) sb[threadIdx.x] += sb[threadIdx.x + off];
    __syncthreads();
  }
  if (threadIdx.x == 0) out[(size_t)B_DIM * NITEM + B_DIM] = -sb[0] / (float)B_DIM;
}

extern "C" void kernel_launch(void* const* d_in, const int* in_sizes, int n_in,
                              void* d_out, int out_size, void* d_ws, size_t ws_size,
                              hipStream_t stream) {
  const int* item_ids = (const int*)d_in[0];
  const int* item_len = (const int*)d_in[1];
  const int* ent_ids = (const int*)d_in[2];
  const int* ent_len = (const int*)d_in[3];
  const int* word_ids = (const int*)d_in[4];
  const int* word_len = (const int*)d_in[5];
  const int* labels = (const int*)d_in[6];
  const float* item_emb = (const float*)d_in[7];
  const float* ent_emb = (const float*)d_in[8];
  const float* word_emb = (const float*)d_in[9];
  const float* W1 = (const float*)d_in[10];
  const float* b1 = (const float*)d_in[11];
  const float* W2 = (const float*)d_in[12];
  const float* b2 = (const float*)d_in[13];

  float* out = (float*)d_out;
  char* ws = (char*)d_ws;
  unsigned short* u_bf = (unsigned short*)ws;                    // 1 MB  [1024][512] bf16
  unsigned short* h_bf = (unsigned short*)(ws + (1 << 20));      // 4 MB  [1024][2048] bf16
  float* rms = (float*)(ws + 6 * (1 << 20));                     // [2][1024] row max / sumexp
  float* row_lp = rms + 2 * B_DIM;                               // [1024]
  float* logits = out;  // logits computed into probs slot, overwritten in-place by smax2

  mean_kernel<<<2 * B_DIM, 256, 0, stream>>>(item_ids, item_len, ent_ids, ent_len, word_ids,
                                             word_len, item_emb, ent_emb, word_emb, u_bf);
  gemm_bias<512, 2048, 0><<<dim3(8, 16), 256, 0, stream>>>(u_bf, W1, b1, h_bf, nullptr);
  gemm_bias<2048, 50000, 1><<<dim3(8, 391), 256, 0, stream>>>(h_bf, W2, b2, nullptr, logits);
  smax1<<<B_DIM, 256, 0, stream>>>(logits, rms);
  smax2<<<B_DIM, 256, 0, stream>>>(logits, rms, labels, row_lp);
  fin<<<1, 256, 0, stream>>>(row_lp, labels, out);
}

// Round 2
// 699.348 us; speedup vs baseline: 1.0554x; 1.0554x over previous
//
#include <hip/hip_runtime.h>
#include <cstdint>
#include <cstddef>

typedef __attribute__((ext_vector_type(8))) short bf16x8;
typedef __attribute__((ext_vector_type(4))) float f32x4;

#define B_DIM 1024
#define L_SEQ 50
#define H_DIM 512
#define NITEM 50000
#define PSTRIDE 400  // >= 391 n-tiles

// fp32 -> bf16 round-to-nearest-even (finite inputs)
__device__ __forceinline__ unsigned short f2bf(float x) {
  unsigned u = __float_as_uint(x);
  return (unsigned short)((u + 0x7fffu + ((u >> 16) & 1u)) >> 16);
}
__device__ __forceinline__ unsigned pack2(float lo, float hi) {
  return (unsigned)f2bf(lo) | ((unsigned)f2bf(hi) << 16);
}

// ---------------- fused 3-table masked mean -> u (bf16 [B][H]) ----------------
__global__ void mean_kernel(const int* __restrict__ item_ids, const int* __restrict__ item_len,
                            const int* __restrict__ ent_ids, const int* __restrict__ ent_len,
                            const int* __restrict__ word_ids, const int* __restrict__ word_len,
                            const float* __restrict__ item_emb, const float* __restrict__ ent_emb,
                            const float* __restrict__ word_emb, unsigned short* __restrict__ u_bf) {
  const int b = blockIdx.x >> 1;
  const int col = ((blockIdx.x & 1) << 8) + threadIdx.x;
  float out = 0.f;
  {
    const int len = item_len[b]; float a = 0.f;
#pragma unroll 4
    for (int l = 0; l < len; ++l) a += item_emb[(size_t)item_ids[b * L_SEQ + l] * H_DIM + col];
    out += a / (float)(len > 0 ? len : 1);
  }
  {
    const int len = ent_len[b]; float a = 0.f;
#pragma unroll 4
    for (int l = 0; l < len; ++l) a += ent_emb[(size_t)ent_ids[b * L_SEQ + l] * H_DIM + col];
    out += a / (float)(len > 0 ? len : 1);
  }
  {
    const int len = word_len[b]; float a = 0.f;
#pragma unroll 4
    for (int l = 0; l < len; ++l) a += word_emb[(size_t)word_ids[b * L_SEQ + l] * H_DIM + col];
    out += a / (float)(len > 0 ? len : 1);
  }
  u_bf[b * H_DIM + col] = f2bf(out / 3.f);
}

// ---------------- bf16 MFMA GEMM: C[M][N] = A[M][K](bf16) * B[K][N](f32->bf16) + bias ----------
// BM=256, BN=128, BK=64. 512 threads = 8 waves (4m x 2n), wave tile 64x64.
// A LDS: [row][64k] bf16, 16B-chunk XOR swizzle (chunk ^= row&7)  -> conflict-free b128 reads.
// B LDS: k-chunked [kc=k/8][n] uint4 (8 k x 1 n per chunk)        -> one b128 per fragment.
// EPI==0: relu + bf16 store (GEMM1). EPI==1: f32 logit store + fused per-block row max/sumexp.
template <int K, int N, int EPI>
__global__ __launch_bounds__(512, 2) void gemm_fused(const unsigned short* __restrict__ Ag,
                                                     const float* __restrict__ Bg,
                                                     const float* __restrict__ bias,
                                                     unsigned short* __restrict__ Cbf,
                                                     float* __restrict__ Cf,
                                                     float* __restrict__ pmax,
                                                     float* __restrict__ psum) {
  __shared__ unsigned short As[2][256 * 64];  // 64 KB
  __shared__ uint4 Bs[2][8 * 128];            // 32 KB

  const int tid = threadIdx.x;
  const int lane = tid & 63;
  const int wid = tid >> 6;
  const int m0 = blockIdx.x * 256;
  const int n0 = blockIdx.y * 128;

  // A staging: thread -> (row = tid>>3 [+64q], chunk = tid&7); coalesced 128B/row
  const int arow = tid >> 3;
  const int ach = tid & 7;
  // B staging: thread -> (n2 = 2*lane, kbase = 8*wid); float2 loads coalesced along n
  const int bn = 2 * lane;
  const int bk = 8 * wid;
  const int bcolg = (n0 + bn < N - 2) ? (n0 + bn) : (N - 2);  // clamp ragged edge (masked later)

  uint4 areg[4];
  float2 breg[8];
  f32x4 acc[4][4] = {};

  auto stage_global = [&](int kt) {
    const int k0 = kt * 64;
#pragma unroll
    for (int q = 0; q < 4; ++q)
      areg[q] = *(const uint4*)&Ag[(size_t)(m0 + arow + 64 * q) * K + k0 + 8 * ach];
#pragma unroll
    for (int i = 0; i < 8; ++i)
      breg[i] = *(const float2*)&Bg[(size_t)(k0 + bk + i) * N + bcolg];
  };

  auto stage_lds = [&](int buf) {
#pragma unroll
    for (int q = 0; q < 4; ++q) {
      const int row = arow + 64 * q;
      *(uint4*)&As[buf][row * 64 + ((8 * ach) ^ ((row & 7) * 8))] = areg[q];
    }
    uint4 c0, c1;
    c0.x = pack2(breg[0].x, breg[1].x); c0.y = pack2(breg[2].x, breg[3].x);
    c0.z = pack2(breg[4].x, breg[5].x); c0.w = pack2(breg[6].x, breg[7].x);
    c1.x = pack2(breg[0].y, breg[1].y); c1.y = pack2(breg[2].y, breg[3].y);
    c1.z = pack2(breg[4].y, breg[5].y); c1.w = pack2(breg[6].y, breg[7].y);
    Bs[buf][wid * 128 + bn] = c0;      // kc = wid, n = bn   (2-way write alias = free)
    Bs[buf][wid * 128 + bn + 1] = c1;  // kc = wid, n = bn+1
  };

  const int wr = wid & 3, wc = wid >> 2;
  const int mw = 64 * wr, nw = 64 * wc;
  const int l15 = lane & 15, kb = lane >> 4;

  auto compute = [&](int buf) {
#pragma unroll
    for (int koi = 0; koi < 2; ++koi) {
      bf16x8 af[4], bfv[4];
#pragma unroll
      for (int i = 0; i < 4; ++i) {
        const int row = mw + 16 * i + l15;
        af[i] = *(const bf16x8*)&As[buf][row * 64 + ((32 * koi + 8 * kb) ^ ((row & 7) * 8))];
      }
#pragma unroll
      for (int j = 0; j < 4; ++j)
        bfv[j] = *(const bf16x8*)&Bs[buf][(4 * koi + kb) * 128 + nw + 16 * j + l15];
#pragma unroll
      for (int i = 0; i < 4; ++i)
#pragma unroll
        for (int j = 0; j < 4; ++j)
          acc[i][j] = __builtin_amdgcn_mfma_f32_16x16x32_bf16(af[i], bfv[j], acc[i][j], 0, 0, 0);
    }
  };

  const int NT = K / 64;
  stage_global(0);
  stage_lds(0);
  __syncthreads();
  for (int t = 0; t < NT; ++t) {
    const int cur = t & 1;
    if (t + 1 < NT) stage_global(t + 1);  // issue next-tile loads early
    compute(cur);
    if (t + 1 < NT) stage_lds(cur ^ 1);   // vmcnt wait lands here, after compute
    __syncthreads();
  }

  // ---- epilogue: C/D layout col=lane&15, row=(lane>>4)*4+reg ----
  float bv[4];
  bool val[4];
#pragma unroll
  for (int j = 0; j < 4; ++j) {
    const int cg = n0 + nw + 16 * j + l15;
    val[j] = (cg < N);
    bv[j] = bias[val[j] ? cg : 0];
  }
#pragma unroll
  for (int i = 0; i < 4; ++i) {
    const int rbase = m0 + mw + 16 * i + 4 * kb;
#pragma unroll
    for (int j = 0; j < 4; ++j) {
      if (val[j]) {
        const int cg = n0 + nw + 16 * j + l15;
#pragma unroll
        for (int r = 0; r < 4; ++r) {
          const float v = acc[i][j][r] + bv[j];
          if (EPI == 0)
            Cbf[(size_t)(rbase + r) * N + cg] = f2bf(v > 0.f ? v : 0.f);
          else
            Cf[(size_t)(rbase + r) * N + cg] = v;
        }
      }
    }
  }

  if constexpr (EPI == 1) {
    // fused softmax pass-1 partials: per-row max & sumexp over this block's 128 cols
    float* redm = (float*)&As[0][0];  // 512 floats (reuse LDS; k-loop done)
    float* reds = redm + 512;
#pragma unroll
    for (int i = 0; i < 4; ++i) {
#pragma unroll
      for (int r = 0; r < 4; ++r) {
        float mx = -3.0e38f;
#pragma unroll
        for (int j = 0; j < 4; ++j)
          if (val[j]) mx = fmaxf(mx, acc[i][j][r] + bv[j]);
#pragma unroll
        for (int d = 1; d < 16; d <<= 1) mx = fmaxf(mx, __shfl_xor(mx, d));
        float s = 0.f;
#pragma unroll
        for (int j = 0; j < 4; ++j)
          if (val[j]) s += expf(acc[i][j][r] + bv[j] - mx);
#pragma unroll
        for (int d = 1; d < 16; d <<= 1) s += __shfl_xor(s, d);
        if (l15 == 0) {
          const int rl = mw + 16 * i + 4 * kb + r;  // block-local row
          redm[wc * 256 + rl] = mx;
          reds[wc * 256 + rl] = s;
        }
      }
    }
    __syncthreads();
    if (tid < 256) {
      const float ma = redm[tid], mb = redm[256 + tid];
      const float mm = fmaxf(ma, mb);
      const float ss = reds[tid] * expf(ma - mm) + reds[256 + tid] * expf(mb - mm);
      pmax[(size_t)(m0 + tid) * PSTRIDE + blockIdx.y] = mm;
      psum[(size_t)(m0 + tid) * PSTRIDE + blockIdx.y] = ss;
    }
  }
}

// ---------------- reduce per-block partials -> row max & sumexp ----------------
__global__ void smax1r(const float* __restrict__ pmax, const float* __restrict__ psum,
                       float* __restrict__ rms, int ntiles) {
  const int b = blockIdx.x;
  const int l = threadIdx.x;  // 64
  float m = -3.4e38f, s = 0.f;
  for (int i = l; i < ntiles; i += 64) {
    const float pm = pmax[(size_t)b * PSTRIDE + i];
    const float ps = psum[(size_t)b * PSTRIDE + i];
    const float nm = fmaxf(m, pm);
    s = s * expf(m - nm) + ps * expf(pm - nm);
    m = nm;
  }
  for (int d = 1; d < 64; d <<= 1) {
    const float om = __shfl_xor(m, d), os = __shfl_xor(s, d);
    const float nm = fmaxf(m, om);
    s = s * expf(m - nm) + os * expf(om - nm);
    m = nm;
  }
  if (l == 0) {
    rms[b] = m;
    rms[B_DIM + b] = s;
  }
}

// ---------------- softmax pass 2: probs in-place + log_softmax(probs) at label ----------------
// max(probs) = exp(m-m)/Z = 1/Z is known analytically -> no online max needed.
__global__ void smax2(float* __restrict__ buf, const float* __restrict__ rms,
                      const int* __restrict__ labels, float* __restrict__ row_lp) {
  const int b = blockIdx.x;
  float4* p = (float4*)(buf + (size_t)b * NITEM);
  const float m = rms[b];
  const float inv = 1.f / rms[B_DIM + b];  // = max(probs)
  const int lab = labels[b];
  __shared__ float s_pl;
  __shared__ float ss[256];
  float s2 = 0.f;
  for (int i = threadIdx.x; i < NITEM / 4; i += 256) {
    const float4 v = p[i];
    float pr[4];
#pragma unroll
    for (int j = 0; j < 4; ++j) {
      pr[j] = expf((&v.x)[j] - m) * inv;
      s2 += expf(pr[j] - inv);
    }
    float4 w;
    w.x = pr[0]; w.y = pr[1]; w.z = pr[2]; w.w = pr[3];
    p[i] = w;
    if ((lab >> 2) == i) s_pl = pr[lab & 3];
  }
  ss[threadIdx.x] = s2;
  __syncthreads();
  for (int off = 128; off > 0; off >>= 1) {
    if (threadIdx.x < off) ss[threadIdx.x] += ss[threadIdx.x + off];
    __syncthreads();
  }
  if (threadIdx.x == 0) row_lp[b] = s_pl - (inv + logf(ss[0]));
}

// ---------------- finalize: labels (as float) + loss ----------------
__global__ void fin(const float* __restrict__ row_lp, const int* __restrict__ labels,
                    float* __restrict__ out) {
  __shared__ float sb[256];
  float a = 0.f;
  for (int i = threadIdx.x; i < B_DIM; i += 256) {
    a += row_lp[i];
    out[(size_t)B_DIM * NITEM + i] = (float)labels[i];
  }
  sb[threadIdx.x] = a;
  __syncthreads();
  for (int off = 128; off > 0; off >>= 1) {
    if (threadIdx.x < off) sb[threadIdx.x] += sb[threadIdx.x + off];
    __syncthreads();
  }
  if (threadIdx.x == 0) out[(size_t)B_DIM * NITEM + B_DIM] = -sb[0] / (float)B_DIM;
}

extern "C" void kernel_launch(void* const* d_in, const int* in_sizes, int n_in,
                              void* d_out, int out_size, void* d_ws, size_t ws_size,
                              hipStream_t stream) {
  const int* item_ids = (const int*)d_in[0];
  const int* item_len = (const int*)d_in[1];
  const int* ent_ids = (const int*)d_in[2];
  const int* ent_len = (const int*)d_in[3];
  const int* word_ids = (const int*)d_in[4];
  const int* word_len = (const int*)d_in[5];
  const int* labels = (const int*)d_in[6];
  const float* item_emb = (const float*)d_in[7];
  const float* ent_emb = (const float*)d_in[8];
  const float* word_emb = (const float*)d_in[9];
  const float* W1 = (const float*)d_in[10];
  const float* b1 = (const float*)d_in[11];
  const float* W2 = (const float*)d_in[12];
  const float* b2 = (const float*)d_in[13];

  float* out = (float*)d_out;
  char* ws = (char*)d_ws;
  unsigned short* u_bf = (unsigned short*)ws;                 // 1 MB   [1024][512] bf16
  unsigned short* h_bf = (unsigned short*)(ws + (1 << 20));   // 4 MB   [1024][2048] bf16
  float* pmax = (float*)(ws + 5 * (1 << 20));                 // 1.6 MB [1024][400]
  float* psum = (float*)(ws + 7 * (1 << 20));                 // 1.6 MB [1024][400]
  float* rms = (float*)(ws + 9 * (1 << 20));                  // [2][1024]
  float* row_lp = rms + 2 * B_DIM;                            // [1024]
  float* logits = out;  // logits into probs slot, overwritten in-place by smax2

  mean_kernel<<<2 * B_DIM, 256, 0, stream>>>(item_ids, item_len, ent_ids, ent_len, word_ids,
                                             word_len, item_emb, ent_emb, word_emb, u_bf);
  gemm_fused<512, 2048, 0><<<dim3(4, 16), 512, 0, stream>>>(u_bf, W1, b1, h_bf, nullptr,
                                                            nullptr, nullptr);
  gemm_fused<2048, 50000, 1><<<dim3(4, 391), 512, 0, stream>>>(h_bf, W2, b2, nullptr, logits,
                                                               pmax, psum);
  smax1r<<<B_DIM, 64, 0, stream>>>(pmax, psum, rms, 391);
  smax2<<<B_DIM, 256, 0, stream>>>(logits, rms, labels, row_lp);
  fin<<<1, 256, 0, stream>>>(row_lp, labels, out);
}

// Round 3
// 587.807 us; speedup vs baseline: 1.2557x; 1.1898x over previous
//
#include <hip/hip_runtime.h>
#include <cstdint>
#include <cstddef>

typedef __attribute__((ext_vector_type(8))) short bf16x8;
typedef __attribute__((ext_vector_type(4))) float f32x4;

#define B_DIM 1024
#define L_SEQ 50
#define H_DIM 512
#define NITEM 50000
#define PSTRIDE 400

// fp32 -> bf16 round-to-nearest-even (finite inputs)
__device__ __forceinline__ unsigned short f2bf(float x) {
  unsigned u = __float_as_uint(x);
  return (unsigned short)((u + 0x7fffu + ((u >> 16) & 1u)) >> 16);
}
__device__ __forceinline__ unsigned pack2(float lo, float hi) {
  return (unsigned)f2bf(lo) | ((unsigned)f2bf(hi) << 16);
}
__device__ __forceinline__ void gld16(const unsigned short* g, unsigned short* l) {
  __builtin_amdgcn_global_load_lds((const __attribute__((address_space(1))) void*)g,
                                   (__attribute__((address_space(3))) void*)l, 16, 0, 0);
}

// ---------------- fused 3-table masked mean -> u (bf16 [B][H]) ----------------
__global__ void mean_kernel(const int* __restrict__ item_ids, const int* __restrict__ item_len,
                            const int* __restrict__ ent_ids, const int* __restrict__ ent_len,
                            const int* __restrict__ word_ids, const int* __restrict__ word_len,
                            const float* __restrict__ item_emb, const float* __restrict__ ent_emb,
                            const float* __restrict__ word_emb, unsigned short* __restrict__ u_bf) {
  const int b = blockIdx.x >> 1;
  const int col = ((blockIdx.x & 1) << 8) + threadIdx.x;
  float out = 0.f;
  {
    const int len = item_len[b]; float a = 0.f;
#pragma unroll 4
    for (int l = 0; l < len; ++l) a += item_emb[(size_t)item_ids[b * L_SEQ + l] * H_DIM + col];
    out += a / (float)(len > 0 ? len : 1);
  }
  {
    const int len = ent_len[b]; float a = 0.f;
#pragma unroll 4
    for (int l = 0; l < len; ++l) a += ent_emb[(size_t)ent_ids[b * L_SEQ + l] * H_DIM + col];
    out += a / (float)(len > 0 ? len : 1);
  }
  {
    const int len = word_len[b]; float a = 0.f;
#pragma unroll 4
    for (int l = 0; l < len; ++l) a += word_emb[(size_t)word_ids[b * L_SEQ + l] * H_DIM + col];
    out += a / (float)(len > 0 ? len : 1);
  }
  u_bf[b * H_DIM + col] = f2bf(out / 3.f);
}

// ---------------- W[K][N] fp32 -> Wt[N][K] bf16 (LDS tile transpose) ----------------
template <int K, int N>
__global__ void transpose_bf16(const float* __restrict__ W, unsigned short* __restrict__ Wt) {
  __shared__ float tile[64][65];
  const int k0 = blockIdx.x * 64, n0 = blockIdx.y * 64;
  const int tn = threadIdx.x & 63, tk = threadIdx.x >> 6;
  const int nv = (n0 + tn < N) ? n0 + tn : N - 1;
#pragma unroll
  for (int i = 0; i < 16; ++i)
    tile[tk + 4 * i][tn] = W[(size_t)(k0 + tk + 4 * i) * N + nv];
  __syncthreads();
  const int rn = threadIdx.x >> 2, ck = (threadIdx.x & 3) * 16;
  if (n0 + rn < N) {
    uint4 o[2];
    unsigned* po = (unsigned*)&o[0];
#pragma unroll
    for (int c = 0; c < 8; ++c)
      po[c] = pack2(tile[ck + 2 * c][rn], tile[ck + 2 * c + 1][rn]);
    *(uint4*)&Wt[(size_t)(n0 + rn) * K + k0 + ck] = o[0];
    *(uint4*)&Wt[(size_t)(n0 + rn) * K + k0 + ck + 8] = o[1];
  }
}

// ---------------- deep-pipelined bf16 GEMM: C = A[M][K] * Bt[N][K]^T + bias ----------------
// BM=BN=256, BK=32, 512 thr / 8 waves (2m x 4n), wave tile 128x64.
// 4-slot LDS ring (128 KB), global_load_lds staging 2 tiles ahead, s_waitcnt vmcnt(4) (never 0
// in-loop), raw s_barrier, setprio around MFMA cluster, bijective XCD block swizzle.
// Read-swizzle chunk ^= (row>>1)&3 with inverse applied to the per-lane GLOBAL source address.
template <int K, int N, int EPI>
__global__ __launch_bounds__(512, 2) void gemm_tt(const unsigned short* __restrict__ Ag,
                                                  const unsigned short* __restrict__ Btg,
                                                  const float* __restrict__ bias,
                                                  unsigned short* __restrict__ Cbf,
                                                  float* __restrict__ Cf,
                                                  float* __restrict__ pmax,
                                                  float* __restrict__ psum) {
  __shared__ unsigned short lds[4][2][256 * 32];  // [slot][A|B][row*32 + k] = 128 KB

  const int tid = threadIdx.x;
  const int lane = tid & 63;
  const int wid = tid >> 6;

  // bijective XCD swizzle (m204): contiguous wgid chunk per XCD
  const int nwg = gridDim.x;
  const int xcd = blockIdx.x & 7, off = blockIdx.x >> 3;
  const int q = nwg >> 3, r = nwg & 7;
  const int wgid = (xcd < r ? xcd * (q + 1) : r * (q + 1) + (xcd - r) * q) + off;
  const int m0 = (wgid & 3) * 256;
  const int bn = wgid >> 2;
  const int n0 = bn * 256;

  // staging geometry: line L covers rows L*128..+127; thread -> (row, chunk)
  const int srow = wid * 16 + (lane >> 2);
  const int schunk = lane & 3;
  const unsigned short* pa[2];
  const unsigned short* pb[2];
  unsigned short* da[2];
  unsigned short* db[2];
#pragma unroll
  for (int L = 0; L < 2; ++L) {
    const int row = L * 128 + srow;
    const int cg = schunk ^ ((row >> 1) & 3);
    pa[L] = Ag + (size_t)(m0 + row) * K + cg * 8;
    int rg = n0 + row;
    rg = rg < N ? rg : N - 1;  // ragged-N clamp (cols masked at epilogue)
    pb[L] = Btg + (size_t)rg * K + cg * 8;
    da[L] = &lds[0][0][L * 4096 + wid * 512];  // + slot*16384 (+8192 for B); HW adds lane*16B
    db[L] = da[L] + 8192;
  }

  auto stage = [&](int t, int s) {
    const int ko = t * 32;
#pragma unroll
    for (int L = 0; L < 2; ++L) gld16(pa[L] + ko, da[L] + s * 16384);
#pragma unroll
    for (int L = 0; L < 2; ++L) gld16(pb[L] + ko, db[L] + s * 16384);
  };

  const int wr = wid >> 2, wc = wid & 3;
  const int l15 = lane & 15, kb = lane >> 4;
  f32x4 acc[8][4] = {};

  auto compute = [&](int s) {
    bf16x8 af[8], bf[4];
#pragma unroll
    for (int i = 0; i < 8; ++i) {
      const int row = wr * 128 + i * 16 + l15;
      const int c = kb ^ ((row >> 1) & 3);
      af[i] = *(const bf16x8*)&lds[s][0][row * 32 + c * 8];
    }
#pragma unroll
    for (int j = 0; j < 4; ++j) {
      const int col = wc * 64 + j * 16 + l15;
      const int c = kb ^ ((col >> 1) & 3);
      bf[j] = *(const bf16x8*)&lds[s][1][col * 32 + c * 8];
    }
    __builtin_amdgcn_s_setprio(1);
#pragma unroll
    for (int i = 0; i < 8; ++i)
#pragma unroll
      for (int j = 0; j < 4; ++j)
        acc[i][j] = __builtin_amdgcn_mfma_f32_16x16x32_bf16(af[i], bf[j], acc[i][j], 0, 0, 0);
    __builtin_amdgcn_s_setprio(0);
  };

  const int NT = K / 32;
  stage(0, 0);
  stage(1, 1);
  asm volatile("s_waitcnt vmcnt(4)" ::: "memory");  // tile 0 resident, tile 1 in flight
  __builtin_amdgcn_sched_barrier(0);
  __builtin_amdgcn_s_barrier();
  __builtin_amdgcn_sched_barrier(0);
  for (int t = 0; t < NT; ++t) {
    if (t + 2 < NT) stage(t + 2, (t + 2) & 3);  // into slot(t-2): readers done 2 barriers ago
    compute(t & 3);
    if (t + 1 < NT) {
      if (t + 2 < NT)
        asm volatile("s_waitcnt vmcnt(4)" ::: "memory");  // tile t+1 resident, t+2 in flight
      else
        asm volatile("s_waitcnt vmcnt(0)" ::: "memory");  // epilogue drain
      __builtin_amdgcn_sched_barrier(0);
      __builtin_amdgcn_s_barrier();
      __builtin_amdgcn_sched_barrier(0);
    }
  }

  // ---- epilogue: C/D layout col=lane&15, row=(lane>>4)*4+reg ----
  float bv[4];
  bool val[4];
#pragma unroll
  for (int j = 0; j < 4; ++j) {
    const int cg = n0 + wc * 64 + 16 * j + l15;
    val[j] = (cg < N);
    bv[j] = bias[val[j] ? cg : 0];
  }
#pragma unroll
  for (int i = 0; i < 8; ++i) {
    const int rbase = m0 + wr * 128 + 16 * i + 4 * kb;
#pragma unroll
    for (int j = 0; j < 4; ++j) {
      if (val[j]) {
        const int cg = n0 + wc * 64 + 16 * j + l15;
#pragma unroll
        for (int rr = 0; rr < 4; ++rr) {
          const float v = acc[i][j][rr] + bv[j];
          if (EPI == 0)
            Cbf[(size_t)(rbase + rr) * N + cg] = f2bf(v > 0.f ? v : 0.f);
          else
            Cf[(size_t)(rbase + rr) * N + cg] = v;
        }
      }
    }
  }

  if constexpr (EPI == 1) {
    // fused softmax pass-1 partials over this block's 256 cols
    float* redm = (float*)&lds[0][0][0];  // 4*256 floats (slot0 area; last reads hit slot 3)
    float* reds = redm + 1024;
#pragma unroll
    for (int i = 0; i < 8; ++i) {
#pragma unroll
      for (int rr = 0; rr < 4; ++rr) {
        float mx = -3.0e38f;
#pragma unroll
        for (int j = 0; j < 4; ++j)
          if (val[j]) mx = fmaxf(mx, acc[i][j][rr] + bv[j]);
#pragma unroll
        for (int d = 1; d < 16; d <<= 1) mx = fmaxf(mx, __shfl_xor(mx, d));
        float s = 0.f;
#pragma unroll
        for (int j = 0; j < 4; ++j)
          if (val[j]) s += expf(acc[i][j][rr] + bv[j] - mx);
#pragma unroll
        for (int d = 1; d < 16; d <<= 1) s += __shfl_xor(s, d);
        if (l15 == 0) {
          const int rw = wr * 128 + 16 * i + 4 * kb + rr;
          redm[wc * 256 + rw] = mx;
          reds[wc * 256 + rw] = s;
        }
      }
    }
    __syncthreads();
    if (tid < 256) {
      float mm = redm[tid], ss = reds[tid];
#pragma unroll
      for (int w = 1; w < 4; ++w) {
        const float ma = redm[w * 256 + tid], sa = reds[w * 256 + tid];
        const float nm = fmaxf(mm, ma);
        ss = ss * expf(mm - nm) + sa * expf(ma - nm);
        mm = nm;
      }
      pmax[(size_t)(m0 + tid) * PSTRIDE + bn] = mm;
      psum[(size_t)(m0 + tid) * PSTRIDE + bn] = ss;
    }
  }
}

// ======== fallback (round-2) GEMM, used when ws is too small for the bf16 W copies ========
template <int K, int N, int EPI>
__global__ __launch_bounds__(512, 2) void gemm_fused(const unsigned short* __restrict__ Ag,
                                                     const float* __restrict__ Bg,
                                                     const float* __restrict__ bias,
                                                     unsigned short* __restrict__ Cbf,
                                                     float* __restrict__ Cf,
                                                     float* __restrict__ pmax,
                                                     float* __restrict__ psum) {
  __shared__ unsigned short As[2][256 * 64];
  __shared__ uint4 Bs[2][8 * 128];
  const int tid = threadIdx.x;
  const int lane = tid & 63;
  const int wid = tid >> 6;
  const int m0 = blockIdx.x * 256;
  const int n0 = blockIdx.y * 128;
  const int arow = tid >> 3;
  const int ach = tid & 7;
  const int bn = 2 * lane;
  const int bk = 8 * wid;
  const int bcolg = (n0 + bn < N - 2) ? (n0 + bn) : (N - 2);
  uint4 areg[4];
  float2 breg[8];
  f32x4 acc[4][4] = {};
  auto stage_global = [&](int kt) {
    const int k0 = kt * 64;
#pragma unroll
    for (int qq = 0; qq < 4; ++qq)
      areg[qq] = *(const uint4*)&Ag[(size_t)(m0 + arow + 64 * qq) * K + k0 + 8 * ach];
#pragma unroll
    for (int i = 0; i < 8; ++i) breg[i] = *(const float2*)&Bg[(size_t)(k0 + bk + i) * N + bcolg];
  };
  auto stage_lds = [&](int buf) {
#pragma unroll
    for (int qq = 0; qq < 4; ++qq) {
      const int row = arow + 64 * qq;
      *(uint4*)&As[buf][row * 64 + ((8 * ach) ^ ((row & 7) * 8))] = areg[qq];
    }
    uint4 c0, c1;
    c0.x = pack2(breg[0].x, breg[1].x); c0.y = pack2(breg[2].x, breg[3].x);
    c0.z = pack2(breg[4].x, breg[5].x); c0.w = pack2(breg[6].x, breg[7].x);
    c1.x = pack2(breg[0].y, breg[1].y); c1.y = pack2(breg[2].y, breg[3].y);
    c1.z = pack2(breg[4].y, breg[5].y); c1.w = pack2(breg[6].y, breg[7].y);
    Bs[buf][wid * 128 + bn] = c0;
    Bs[buf][wid * 128 + bn + 1] = c1;
  };
  const int wr = wid & 3, wc = wid >> 2;
  const int mw = 64 * wr, nw = 64 * wc;
  const int l15 = lane & 15, kb = lane >> 4;
  auto compute = [&](int buf) {
#pragma unroll
    for (int koi = 0; koi < 2; ++koi) {
      bf16x8 af[4], bfv[4];
#pragma unroll
      for (int i = 0; i < 4; ++i) {
        const int row = mw + 16 * i + l15;
        af[i] = *(const bf16x8*)&As[buf][row * 64 + ((32 * koi + 8 * kb) ^ ((row & 7) * 8))];
      }
#pragma unroll
      for (int j = 0; j < 4; ++j)
        bfv[j] = *(const bf16x8*)&Bs[buf][(4 * koi + kb) * 128 + nw + 16 * j + l15];
#pragma unroll
      for (int i = 0; i < 4; ++i)
#pragma unroll
        for (int j = 0; j < 4; ++j)
          acc[i][j] = __builtin_amdgcn_mfma_f32_16x16x32_bf16(af[i], bfv[j], acc[i][j], 0, 0, 0);
    }
  };
  const int NT = K / 64;
  stage_global(0);
  stage_lds(0);
  __syncthreads();
  for (int t = 0; t < NT; ++t) {
    const int cur = t & 1;
    if (t + 1 < NT) stage_global(t + 1);
    compute(cur);
    if (t + 1 < NT) stage_lds(cur ^ 1);
    __syncthreads();
  }
  float bv[4];
  bool val[4];
#pragma unroll
  for (int j = 0; j < 4; ++j) {
    const int cg = n0 + nw + 16 * j + l15;
    val[j] = (cg < N);
    bv[j] = bias[val[j] ? cg : 0];
  }
#pragma unroll
  for (int i = 0; i < 4; ++i) {
    const int rbase = m0 + mw + 16 * i + 4 * kb;
#pragma unroll
    for (int j = 0; j < 4; ++j) {
      if (val[j]) {
        const int cg = n0 + nw + 16 * j + l15;
#pragma unroll
        for (int rr = 0; rr < 4; ++rr) {
          const float v = acc[i][j][rr] + bv[j];
          if (EPI == 0)
            Cbf[(size_t)(rbase + rr) * N + cg] = f2bf(v > 0.f ? v : 0.f);
          else
            Cf[(size_t)(rbase + rr) * N + cg] = v;
        }
      }
    }
  }
  if constexpr (EPI == 1) {
    float* redm = (float*)&As[0][0];
    float* reds = redm + 512;
#pragma unroll
    for (int i = 0; i < 4; ++i) {
#pragma unroll
      for (int rr = 0; rr < 4; ++rr) {
        float mx = -3.0e38f;
#pragma unroll
        for (int j = 0; j < 4; ++j)
          if (val[j]) mx = fmaxf(mx, acc[i][j][rr] + bv[j]);
#pragma unroll
        for (int d = 1; d < 16; d <<= 1) mx = fmaxf(mx, __shfl_xor(mx, d));
        float s = 0.f;
#pragma unroll
        for (int j = 0; j < 4; ++j)
          if (val[j]) s += expf(acc[i][j][rr] + bv[j] - mx);
#pragma unroll
        for (int d = 1; d < 16; d <<= 1) s += __shfl_xor(s, d);
        if (l15 == 0) {
          const int rl = mw + 16 * i + 4 * kb + rr;
          redm[wc * 256 + rl] = mx;
          reds[wc * 256 + rl] = s;
        }
      }
    }
    __syncthreads();
    if (tid < 256) {
      const float ma = redm[tid], mb = redm[256 + tid];
      const float mm = fmaxf(ma, mb);
      const float ss = reds[tid] * expf(ma - mm) + reds[256 + tid] * expf(mb - mm);
      pmax[(size_t)(m0 + tid) * PSTRIDE + blockIdx.y] = mm;
      psum[(size_t)(m0 + tid) * PSTRIDE + blockIdx.y] = ss;
    }
  }
}

// ---------------- reduce per-block partials -> row max & sumexp ----------------
__global__ void smax1r(const float* __restrict__ pmax, const float* __restrict__ psum,
                       float* __restrict__ rms, int ntiles) {
  const int b = blockIdx.x;
  const int l = threadIdx.x;
  float m = -3.4e38f, s = 0.f;
  for (int i = l; i < ntiles; i += 64) {
    const float pm = pmax[(size_t)b * PSTRIDE + i];
    const float ps = psum[(size_t)b * PSTRIDE + i];
    const float nm = fmaxf(m, pm);
    s = s * expf(m - nm) + ps * expf(pm - nm);
    m = nm;
  }
  for (int d = 1; d < 64; d <<= 1) {
    const float om = __shfl_xor(m, d), os = __shfl_xor(s, d);
    const float nm = fmaxf(m, om);
    s = s * expf(m - nm) + os * expf(om - nm);
    m = nm;
  }
  if (l == 0) {
    rms[b] = m;
    rms[B_DIM + b] = s;
  }
}

// ---------------- softmax pass 2: probs in-place + log_softmax(probs) at label ----------------
__global__ void smax2(float* __restrict__ buf, const float* __restrict__ rms,
                      const int* __restrict__ labels, float* __restrict__ row_lp) {
  const int b = blockIdx.x;
  float4* p = (float4*)(buf + (size_t)b * NITEM);
  const float m = rms[b];
  const float inv = 1.f / rms[B_DIM + b];  // = max(probs)
  const int lab = labels[b];
  __shared__ float s_pl;
  __shared__ float ss[256];
  float s2 = 0.f;
  for (int i = threadIdx.x; i < NITEM / 4; i += 256) {
    const float4 v = p[i];
    float pr[4];
#pragma unroll
    for (int j = 0; j < 4; ++j) {
      pr[j] = expf((&v.x)[j] - m) * inv;
      s2 += expf(pr[j] - inv);
    }
    float4 w;
    w.x = pr[0]; w.y = pr[1]; w.z = pr[2]; w.w = pr[3];
    p[i] = w;
    if ((lab >> 2) == i) s_pl = pr[lab & 3];
  }
  ss[threadIdx.x] = s2;
  __syncthreads();
  for (int off = 128; off > 0; off >>= 1) {
    if (threadIdx.x < off) ss[threadIdx.x] += ss[threadIdx.x + off];
    __syncthreads();
  }
  if (threadIdx.x == 0) row_lp[b] = s_pl - (inv + logf(ss[0]));
}

// ---------------- finalize: labels (as float) + loss ----------------
__global__ void fin(const float* __restrict__ row_lp, const int* __restrict__ labels,
                    float* __restrict__ out) {
  __shared__ float sb[256];
  float a = 0.f;
  for (int i = threadIdx.x; i < B_DIM; i += 256) {
    a += row_lp[i];
    out[(size_t)B_DIM * NITEM + i] = (float)labels[i];
  }
  sb[threadIdx.x] = a;
  __syncthreads();
  for (int off = 128; off > 0; off >>= 1) {
    if (threadIdx.x < off) sb[threadIdx.x] += sb[threadIdx.x + off];
    __syncthreads();
  }
  if (threadIdx.x == 0) out[(size_t)B_DIM * NITEM + B_DIM] = -sb[0] / (float)B_DIM;
}

extern "C" void kernel_launch(void* const* d_in, const int* in_sizes, int n_in,
                              void* d_out, int out_size, void* d_ws, size_t ws_size,
                              hipStream_t stream) {
  const int* item_ids = (const int*)d_in[0];
  const int* item_len = (const int*)d_in[1];
  const int* ent_ids = (const int*)d_in[2];
  const int* ent_len = (const int*)d_in[3];
  const int* word_ids = (const int*)d_in[4];
  const int* word_len = (const int*)d_in[5];
  const int* labels = (const int*)d_in[6];
  const float* item_emb = (const float*)d_in[7];
  const float* ent_emb = (const float*)d_in[8];
  const float* word_emb = (const float*)d_in[9];
  const float* W1 = (const float*)d_in[10];
  const float* b1 = (const float*)d_in[11];
  const float* W2 = (const float*)d_in[12];
  const float* b2 = (const float*)d_in[13];

  float* out = (float*)d_out;
  char* ws = (char*)d_ws;
  unsigned short* u_bf = (unsigned short*)ws;                 // 1 MB   [1024][512] bf16
  unsigned short* h_bf = (unsigned short*)(ws + (1 << 20));   // 4 MB   [1024][2048] bf16
  float* pmax = (float*)(ws + 5 * (1 << 20));                 // 1.6 MB [1024][400]
  float* psum = (float*)(ws + 7 * (1 << 20));                 // 1.6 MB
  float* rms = (float*)(ws + 9 * (1 << 20));                  // [2][1024]
  float* row_lp = rms + 2 * B_DIM;
  unsigned short* W1t = (unsigned short*)(ws + 10 * (1 << 20));  // 2 MB [2048][512] bf16
  unsigned short* W2t = (unsigned short*)(ws + 16 * (1 << 20));  // 204.8 MB [50000][2048] bf16
  float* logits = out;

  const size_t need = (size_t)16 * (1 << 20) + (size_t)NITEM * 2048 * 2;
  const bool fast = ws_size >= need;

  mean_kernel<<<2 * B_DIM, 256, 0, stream>>>(item_ids, item_len, ent_ids, ent_len, word_ids,
                                             word_len, item_emb, ent_emb, word_emb, u_bf);
  if (fast) {
    transpose_bf16<512, 2048><<<dim3(8, 32), 256, 0, stream>>>(W1, W1t);
    transpose_bf16<2048, NITEM><<<dim3(32, 782), 256, 0, stream>>>(W2, W2t);
    gemm_tt<512, 2048, 0><<<4 * 8, 512, 0, stream>>>(u_bf, W1t, b1, h_bf, nullptr, nullptr,
                                                     nullptr);
    gemm_tt<2048, NITEM, 1><<<4 * 196, 512, 0, stream>>>(h_bf, W2t, b2, nullptr, logits, pmax,
                                                         psum);
    smax1r<<<B_DIM, 64, 0, stream>>>(pmax, psum, rms, 196);
  } else {
    gemm_fused<512, 2048, 0><<<dim3(4, 16), 512, 0, stream>>>(u_bf, W1, b1, h_bf, nullptr,
                                                              nullptr, nullptr);
    gemm_fused<2048, NITEM, 1><<<dim3(4, 391), 512, 0, stream>>>(h_bf, W2, b2, nullptr, logits,
                                                                 pmax, psum);
    smax1r<<<B_DIM, 64, 0, stream>>>(pmax, psum, rms, 391);
  }
  smax2<<<B_DIM, 256, 0, stream>>>(logits, rms, labels, row_lp);
  fin<<<1, 256, 0, stream>>>(row_lp, labels, out);
}